// Round 20
// baseline (193.195 us; speedup 1.0000x reference)
//
#include <hip/hip_runtime.h>

// out[b,o,h,w] = sum_{c,k} (coef[k]/12.5) * rint( sum_j (12.5*w[k,c,o,j])*x_j + 12.5*b[k,c,o] )
// R17 = R16 (67.5us: 4 rows/wave, 4-way c-split, XCD-keyed grid, x ping-pong) with the
//   packed halves carrying TWO K-BITS instead of two rows:
//   s_{k0,k1} = pk_fma( {w_k0j,w_k1j} (SGPR pair, direct from [j][kpair] layout),
//               broadcast(tap_j) (op_sel, zero movs), s )
//   -> deletes ALL tap-pair packing movs (~30/c-step) and weight splats.
//   Taps stay 18 un-packed scalars; per-k FMA order unchanged (same quant bins);
//   outer k-sum reassociated (even-k half + odd-k half) -> absmax ~0.081 expected.

typedef float v2f __attribute__((ext_vector_type(2)));

#define NB     8
#define NC     32
#define NO     32
#define NH     64
#define NW     64
#define NBATCH 8
#define PLANE  (NH * NW)
#define WCSTEP 80                  // dwords per c step: [j:10][k:8]
#define CQUART 8                   // channels per wave

// wq layout: [o:32][c:32][j:10][k:8]; j<9: 12.5*w_j, j=9: 12.5*bias. k-pairs contiguous.
__global__ void prep_wq(const float* __restrict__ w, const float* __restrict__ bias,
                        float* __restrict__ wq) {
    int idx = blockIdx.x * 256 + threadIdx.x;      // (o*32+c)*8+k
    if (idx >= NC * NO * NB) return;
    int k = idx & 7;
    int c = (idx >> 3) & 31;
    int o = idx >> 8;
    int ch = c * NO + o;                           // channel in original [k][1024] layout
    const float* ws = w + ((size_t)k * (NC * NO) + ch) * 9;
    float* dst = wq + ((size_t)(o * NC + c) * 10) * 8 + k;   // stride 8 per j
#pragma unroll
    for (int j = 0; j < 9; ++j) dst[j * 8] = 12.5f * ws[j];
    dst[9 * 8] = 12.5f * bias[k * (NC * NO) + ch];
}

// lane w receives lane w-1's value; lane 0 -> 0 (bound_ctrl). (wave_shr:1 = 0x138)
__device__ __forceinline__ float dpp_left(float v) {
    return __builtin_bit_cast(float, __builtin_amdgcn_update_dpp(
        0, __builtin_bit_cast(int, v), 0x138, 0xf, 0xf, true));
}
// lane w receives lane w+1's value; lane 63 -> 0. (wave_shl:1 = 0x130)
__device__ __forceinline__ float dpp_right(float v) {
    return __builtin_bit_cast(float, __builtin_amdgcn_update_dpp(
        0, __builtin_bit_cast(int, v), 0x130, 0xf, 0xf, true));
}

// One channel-step, 4 rows, k-paired packed math.
// wv = (v2f*)(per-c weight block): wv[j*4+kp] = {w_{2kp,j}, w_{2kp+1,j}}, wv[36+kp] = bias pair.
__device__ __forceinline__ void step4(
        float xm1, float x0, float x1, float x2, float x3, float x4,
        bool top, bool bot, const v2f* __restrict__ wv,
        v2f& acc0, v2f& acc1, v2f& acc2, v2f& acc3,
        const v2f* __restrict__ ckp) {
    if (!top) xm1 = 0.f;                           // wave-uniform
    if (!bot) x4  = 0.f;

    float tC[6] = {xm1, x0, x1, x2, x3, x4};       // raw rows h0-1 .. h0+4
    float tL[6], tR[6];
#pragma unroll
    for (int r = 0; r < 6; ++r) { tL[r] = dpp_left(tC[r]); tR[r] = dpp_right(tC[r]); }

#pragma unroll
    for (int r = 0; r < 4; ++r) {                  // output rows h0+r
        v2f a = (r == 0) ? acc0 : (r == 1) ? acc1 : (r == 2) ? acc2 : acc3;
#pragma unroll
        for (int kp = 0; kp < 4; ++kp) {           // k-pairs {0,1},{2,3},{4,5},{6,7}
            v2f s = wv[36 + kp];                   // {bias_k0, bias_k1}
#pragma unroll
            for (int j = 0; j < 9; ++j) {          // same tap order as R8..R16 (canary)
                const int rr = r + j / 3;
                const int cc = j % 3;
                float tap = (cc == 0) ? tL[rr] : (cc == 1) ? tC[rr] : tR[rr];
                v2f tv; tv.x = tap; tv.y = tap;    // broadcast (op_sel, ideally zero movs)
                s = __builtin_elementwise_fma(wv[j * 4 + kp], tv, s);
            }
            v2f rr2; rr2.x = rintf(s.x); rr2.y = rintf(s.y);
            a = __builtin_elementwise_fma(ckp[kp], rr2, a);
        }
        if (r == 0) acc0 = a; else if (r == 1) acc1 = a;
        else if (r == 2) acc2 = a; else acc3 = a;
    }
}

// Block = 4 waves (256 thr) = one (b, o, row-quad) x 4 c-quarters.
// Grid (8 hb, hq*32+o, b): id%8 = hb (XCD key); resident blocks share o (K$ slab).
__global__ __launch_bounds__(256, 8) void demolition_conv(
        const float* __restrict__ x, const float* __restrict__ wq,
        float* __restrict__ out) {
    __shared__ float part[3][4][64];               // written by cq=1..3

    const int tid  = threadIdx.x;
    const int w    = tid & 63;
    const int cq   = tid >> 6;                     // 0..3 (c-quarter)
    const int hb   = blockIdx.x;                   // 0..7 (XCD key)
    const int o    = blockIdx.y & 31;              // 0..31
    const int hq   = blockIdx.y >> 5;              // 0..1 (row-quad within 8-row slab)
    const int b    = blockIdx.z;
    const int h0   = hb * 8 + hq * 4;              // 0,4,...,60

    v2f ckp[4];
#pragma unroll
    for (int kp = 0; kp < 4; ++kp) {
        const int k0 = 2 * kp, k1 = 2 * kp + 1;
        ckp[kp].x = (k0 == 0) ? (-128.f / 127.f / 12.5f)
                              : ((float)(1 << (k0 - 1)) / 127.f / 12.5f);
        ckp[kp].y = (float)(1 << (k1 - 1)) / 127.f / 12.5f;
    }

    v2f acc0 = {0.f, 0.f}, acc1 = {0.f, 0.f}, acc2 = {0.f, 0.f}, acc3 = {0.f, 0.f};

    const bool top = (h0 > 0), bot = (h0 < NH - 4);   // wave-uniform
    const int  rT  = top ? -NW : 0;           // clamped address for row h0-1
    const int  rB  = bot ? 4 * NW : 3 * NW;   // clamped address for row h0+4

    const float* xc = x + (((size_t)b * NC + cq * CQUART) * NH + h0) * NW + w;
    const v2f* wv = reinterpret_cast<const v2f*>(
        wq + __builtin_amdgcn_readfirstlane((o * NC + cq * CQUART) * WCSTEP));

    // prologue: raw loads for first channel (ping)
    float am1 = xc[rT], a0 = xc[0], a1 = xc[NW], a2 = xc[2 * NW],
          a3  = xc[3 * NW], a4 = xc[rB];

#pragma unroll 1
    for (int c = 0; c < CQUART; c += 2) {
        // prefetch c+1 (pong) — issued BEFORE compute of c
        const float* xn = xc + PLANE;
        float bm1 = xn[rT], b0 = xn[0], b1 = xn[NW], b2 = xn[2 * NW],
              b3  = xn[3 * NW], b4 = xn[rB];
        step4(am1, a0, a1, a2, a3, a4, top, bot, wv, acc0, acc1, acc2, acc3, ckp);
        wv += WCSTEP / 2;

        // prefetch c+2 (ping); clamp at tail (wave-uniform, loads harmless & unused)
        const float* xm = (c + 2 < CQUART) ? xn + PLANE : xn;
        am1 = xm[rT]; a0 = xm[0]; a1 = xm[NW]; a2 = xm[2 * NW];
        a3  = xm[3 * NW]; a4 = xm[rB];
        step4(bm1, b0, b1, b2, b3, b4, top, bot, wv, acc0, acc1, acc2, acc3, ckp);
        wv += WCSTEP / 2;

        xc = xm;
    }

    // horizontal k-halves sum, then combine the four c-quarters (post-rint partials)
    float r0 = acc0.x + acc0.y, r1 = acc1.x + acc1.y,
          r2 = acc2.x + acc2.y, r3 = acc3.x + acc3.y;

    if (cq) {
        part[cq - 1][0][w] = r0;
        part[cq - 1][1][w] = r1;
        part[cq - 1][2][w] = r2;
        part[cq - 1][3][w] = r3;
    }
    __syncthreads();
    if (!cq) {
        float* op = out + (((size_t)b * NO + o) * NH + h0) * NW + w;
        op[0]      = r0 + part[0][0][w] + part[1][0][w] + part[2][0][w];
        op[NW]     = r1 + part[0][1][w] + part[1][1][w] + part[2][1][w];
        op[2 * NW] = r2 + part[0][2][w] + part[1][2][w] + part[2][2][w];
        op[3 * NW] = r3 + part[0][3][w] + part[1][3][w] + part[2][3][w];
    }
}

extern "C" void kernel_launch(void* const* d_in, const int* in_sizes, int n_in,
                              void* d_out, int out_size, void* d_ws, size_t ws_size,
                              hipStream_t stream) {
    const float* x    = (const float*)d_in[0];   // [8,32,64,64]
    const float* wt   = (const float*)d_in[1];   // [8,1024,1,3,3]
    const float* bias = (const float*)d_in[2];   // [8,1024]
    float* out = (float*)d_out;                  // [8,32,64,64]
    float* wq  = (float*)d_ws;                   // 8192*10 floats = 320 KiB

    prep_wq<<<(NC * NO * NB + 255) / 256, 256, 0, stream>>>(wt, bias, wq);

    dim3 grid(8, NO * 2, NBATCH);                // (hb, hq*32+o, b): id%8 == hb (XCD key)
    demolition_conv<<<grid, 256, 0, stream>>>(x, wq, out);
}

// Round 21
// 67.448 us; speedup vs baseline: 2.8643x; 2.8643x over previous
//
#include <hip/hip_runtime.h>

// out[b,o,h,w] = sum_{c,k} (coef[k]/12.5) * rint( sum_j (12.5*w[k,c,o,j])*x_j + 12.5*b[k,c,o] )
// R18 = R16 verbatim (67.46us, best): 4 output rows/wave (2 packed row-pairs, shared tap
// pairs), 4-way c-split, XCD-keyed grid, x ping-pong, [o][c][k][10] weights, LDS combine.
// Reverts R17 (k-pair packing: compiler materialized every packed operand -> 3x busy).
// The pk_fma idiom that lowers cleanly: VGPR-packed taps x SGPR-splat weights. Keep it.

typedef float v2f __attribute__((ext_vector_type(2)));

#define NB     8
#define NC     32
#define NO     32
#define NH     64
#define NW     64
#define NBATCH 8
#define FST    10                  // 9 taps + bias
#define PLANE  (NH * NW)
#define WCSTEP (NB * FST)          // dwords per c step in wq (contiguous per-o stream)
#define CQUART 8                   // channels per wave

// wq layout: [o:32][c:32][k:8][10]; value = 12.5*w, [9] = 12.5*bias
__global__ void prep_wq(const float* __restrict__ w, const float* __restrict__ bias,
                        float* __restrict__ wq) {
    int idx = blockIdx.x * 256 + threadIdx.x;      // (o*32+c)*8+k
    if (idx >= NC * NO * NB) return;
    int k = idx & 7;
    int c = (idx >> 3) & 31;
    int o = idx >> 8;
    int ch = c * NO + o;                           // channel in original [k][1024] layout
    const float* ws = w + ((size_t)k * (NC * NO) + ch) * 9;
    float* dst = wq + (size_t)idx * FST;
#pragma unroll
    for (int j = 0; j < 9; ++j) dst[j] = 12.5f * ws[j];
    dst[9] = 12.5f * bias[k * (NC * NO) + ch];
}

// lane w receives lane w-1's value; lane 0 -> 0 (bound_ctrl). (wave_shr:1 = 0x138)
__device__ __forceinline__ float dpp_left(float v) {
    return __builtin_bit_cast(float, __builtin_amdgcn_update_dpp(
        0, __builtin_bit_cast(int, v), 0x138, 0xf, 0xf, true));
}
// lane w receives lane w+1's value; lane 63 -> 0. (wave_shl:1 = 0x130)
__device__ __forceinline__ float dpp_right(float v) {
    return __builtin_bit_cast(float, __builtin_amdgcn_update_dpp(
        0, __builtin_bit_cast(int, v), 0x130, 0xf, 0xf, true));
}

// One channel-step, 4 rows. Raw center values = input rows h0-1 .. h0+4.
// acc01 = rows (h0,h1), acc23 = rows (h2,h3). Per-row FMA order == R12/R15 (canary).
__device__ __forceinline__ void step4(float xm1, float x0, float x1, float x2,
                                      float x3, float x4,
                                      bool top, bool bot,
                                      const float* __restrict__ wp,
                                      v2f& acc01, v2f& acc23,
                                      const float* __restrict__ ckq) {
    if (!top) xm1 = 0.f;                           // wave-uniform
    if (!bot) x4  = 0.f;

    float lm1 = dpp_left(xm1), l0 = dpp_left(x0), l1 = dpp_left(x1),
          l2  = dpp_left(x2),  l3 = dpp_left(x3), l4 = dpp_left(x4);
    float rm1 = dpp_right(xm1), r0 = dpp_right(x0), r1 = dpp_right(x1),
          r2  = dpp_right(x2),  r3 = dpp_right(x3), r4 = dpp_right(x4);

    // pairs Pc[r] = { row(h0-1+r), row(h0+r) } at column w+c-1, r = 0..4
    v2f PL0, PL1, PL2, PL3, PL4, PC0, PC1, PC2, PC3, PC4, PR0, PR1, PR2, PR3, PR4;
    PL0.x = lm1; PL0.y = l0;  PC0.x = xm1; PC0.y = x0;  PR0.x = rm1; PR0.y = r0;
    PL1.x = l0;  PL1.y = l1;  PC1.x = x0;  PC1.y = x1;  PR1.x = r0;  PR1.y = r1;
    PL2.x = l1;  PL2.y = l2;  PC2.x = x1;  PC2.y = x2;  PR2.x = r1;  PR2.y = r2;
    PL3.x = l2;  PL3.y = l3;  PC3.x = x2;  PC3.y = x3;  PR3.x = r2;  PR3.y = r3;
    PL4.x = l3;  PL4.y = l4;  PC4.x = x3;  PC4.y = x4;  PR4.x = r3;  PR4.y = r4;

#pragma unroll
    for (int k = 0; k < NB; ++k) {
        const float* f = wp + k * FST;             // compile-time imm offsets off scalar base
        v2f s01, s23;
        s01.x = f[9]; s01.y = f[9];                // pre-scaled bias
        s23.x = f[9]; s23.y = f[9];
        v2f w0; w0.x = f[0]; w0.y = f[0];
        v2f w1; w1.x = f[1]; w1.y = f[1];
        v2f w2; w2.x = f[2]; w2.y = f[2];
        s01 = __builtin_elementwise_fma(w0, PL0, s01);  s23 = __builtin_elementwise_fma(w0, PL2, s23);
        s01 = __builtin_elementwise_fma(w1, PC0, s01);  s23 = __builtin_elementwise_fma(w1, PC2, s23);
        s01 = __builtin_elementwise_fma(w2, PR0, s01);  s23 = __builtin_elementwise_fma(w2, PR2, s23);
        v2f w3; w3.x = f[3]; w3.y = f[3];
        v2f w4; w4.x = f[4]; w4.y = f[4];
        v2f w5; w5.x = f[5]; w5.y = f[5];
        s01 = __builtin_elementwise_fma(w3, PL1, s01);  s23 = __builtin_elementwise_fma(w3, PL3, s23);
        s01 = __builtin_elementwise_fma(w4, PC1, s01);  s23 = __builtin_elementwise_fma(w4, PC3, s23);
        s01 = __builtin_elementwise_fma(w5, PR1, s01);  s23 = __builtin_elementwise_fma(w5, PR3, s23);
        v2f w6; w6.x = f[6]; w6.y = f[6];
        v2f w7; w7.x = f[7]; w7.y = f[7];
        v2f w8; w8.x = f[8]; w8.y = f[8];
        s01 = __builtin_elementwise_fma(w6, PL2, s01);  s23 = __builtin_elementwise_fma(w6, PL4, s23);
        s01 = __builtin_elementwise_fma(w7, PC2, s01);  s23 = __builtin_elementwise_fma(w7, PC4, s23);
        s01 = __builtin_elementwise_fma(w8, PR2, s01);  s23 = __builtin_elementwise_fma(w8, PR4, s23);
        v2f rr01; rr01.x = rintf(s01.x); rr01.y = rintf(s01.y);
        v2f rr23; rr23.x = rintf(s23.x); rr23.y = rintf(s23.y);
        v2f cv; cv.x = ckq[k]; cv.y = ckq[k];
        acc01 = __builtin_elementwise_fma(cv, rr01, acc01);
        acc23 = __builtin_elementwise_fma(cv, rr23, acc23);
    }
}

// Block = 4 waves (256 thr) = one (b, o, row-quad) x 4 c-quarters.
// Grid (8 hb, hq*32+o, b): id%8 = hb (XCD key); resident blocks share o (K$ slab).
__global__ __launch_bounds__(256, 8) void demolition_conv(
        const float* __restrict__ x, const float* __restrict__ wq,
        float* __restrict__ out) {
    __shared__ float part[3][4][64];               // written by cq=1..3

    const int tid  = threadIdx.x;
    const int w    = tid & 63;
    const int cq   = tid >> 6;                     // 0..3 (c-quarter)
    const int hb   = blockIdx.x;                   // 0..7 (XCD key)
    const int o    = blockIdx.y & 31;              // 0..31
    const int hq   = blockIdx.y >> 5;              // 0..1 (row-quad within 8-row slab)
    const int b    = blockIdx.z;
    const int h0   = hb * 8 + hq * 4;              // 0,4,...,60

    const float ckq[8] = {
        -128.f / 127.f / 12.5f,  1.f / 127.f / 12.5f,  2.f / 127.f / 12.5f,
           4.f / 127.f / 12.5f,  8.f / 127.f / 12.5f, 16.f / 127.f / 12.5f,
          32.f / 127.f / 12.5f, 64.f / 127.f / 12.5f };

    v2f acc01 = {0.f, 0.f}, acc23 = {0.f, 0.f};

    const bool top = (h0 > 0), bot = (h0 < NH - 4);   // wave-uniform
    const int  rT  = top ? -NW : 0;           // clamped address for row h0-1
    const int  rB  = bot ? 4 * NW : 3 * NW;   // clamped address for row h0+4

    const float* xc = x + (((size_t)b * NC + cq * CQUART) * NH + h0) * NW + w;
    const float* wp = wq + __builtin_amdgcn_readfirstlane(
                          o * (NC * NB * FST) + cq * CQUART * WCSTEP);

    // prologue: raw loads for first channel (ping)
    float am1 = xc[rT], a0 = xc[0], a1 = xc[NW], a2 = xc[2 * NW],
          a3  = xc[3 * NW], a4 = xc[rB];

#pragma unroll 1
    for (int c = 0; c < CQUART; c += 2) {
        // prefetch c+1 (pong) — issued BEFORE compute of c
        const float* xn = xc + PLANE;
        float bm1 = xn[rT], b0 = xn[0], b1 = xn[NW], b2 = xn[2 * NW],
              b3  = xn[3 * NW], b4 = xn[rB];
        step4(am1, a0, a1, a2, a3, a4, top, bot, wp, acc01, acc23, ckq);
        wp += WCSTEP;

        // prefetch c+2 (ping); clamp at tail (wave-uniform, loads harmless & unused)
        const float* xm = (c + 2 < CQUART) ? xn + PLANE : xn;
        am1 = xm[rT]; a0 = xm[0]; a1 = xm[NW]; a2 = xm[2 * NW];
        a3  = xm[3 * NW]; a4 = xm[rB];
        step4(bm1, b0, b1, b2, b3, b4, top, bot, wp, acc01, acc23, ckq);
        wp += WCSTEP;

        xc = xm;
    }

    // combine the four c-quarters (post-rint partials; outer-sum reassociation only)
    if (cq) {
        part[cq - 1][0][w] = acc01.x;
        part[cq - 1][1][w] = acc01.y;
        part[cq - 1][2][w] = acc23.x;
        part[cq - 1][3][w] = acc23.y;
    }
    __syncthreads();
    if (!cq) {
        float* op = out + (((size_t)b * NO + o) * NH + h0) * NW + w;
        op[0]      = acc01.x + part[0][0][w] + part[1][0][w] + part[2][0][w];
        op[NW]     = acc01.y + part[0][1][w] + part[1][1][w] + part[2][1][w];
        op[2 * NW] = acc23.x + part[0][2][w] + part[1][2][w] + part[2][2][w];
        op[3 * NW] = acc23.y + part[0][3][w] + part[1][3][w] + part[2][3][w];
    }
}

extern "C" void kernel_launch(void* const* d_in, const int* in_sizes, int n_in,
                              void* d_out, int out_size, void* d_ws, size_t ws_size,
                              hipStream_t stream) {
    const float* x    = (const float*)d_in[0];   // [8,32,64,64]
    const float* wt   = (const float*)d_in[1];   // [8,1024,1,3,3]
    const float* bias = (const float*)d_in[2];   // [8,1024]
    float* out = (float*)d_out;                  // [8,32,64,64]
    float* wq  = (float*)d_ws;                   // 8192*10 floats = 320 KiB

    prep_wq<<<(NC * NO * NB + 255) / 256, 256, 0, stream>>>(wt, bias, wq);

    dim3 grid(8, NO * 2, NBATCH);                // (hb, hq*32+o, b): id%8 == hb (XCD key)
    demolition_conv<<<grid, 256, 0, stream>>>(x, wq, out);
}